// Round 13
// baseline (380.728 us; speedup 1.0000x reference)
//
#include <hip/hip_runtime.h>
#include <hip/hip_bf16.h>

#define T_TOK 2048
#define DDIM  1024
#define NEXP  8
#define FDIM  4096
#define ROWS  (4096 + 256)

typedef __attribute__((ext_vector_type(8))) short bf16x8;
typedef __attribute__((ext_vector_type(4))) float f32x4;

#define SBW(n) ((((n) >> 3) ^ (n)) & 7)

__device__ __forceinline__ unsigned short f2b(float f) {
  union { float f; unsigned u; } v; v.f = f;
  unsigned r = v.u + 0x7FFF + ((v.u >> 16) & 1);  // RNE
  return (unsigned short)(r >> 16);
}
__device__ __forceinline__ float b2f(unsigned short s) {
  union { unsigned u; float f; } v; v.u = ((unsigned)s) << 16;
  return v.f;
}
__device__ __forceinline__ unsigned cvtpk(float lo, float hi) {
  unsigned r;
  asm("v_cvt_pk_bf16_f32 %0, %1, %2" : "=v"(r) : "v"(lo), "v"(hi));
  return r;
}
__device__ __forceinline__ void gl16(const unsigned short* g, unsigned short* l) {
  __builtin_amdgcn_global_load_lds(
      (const __attribute__((address_space(1))) unsigned int*)(const void*)g,
      (__attribute__((address_space(3))) unsigned int*)(void*)l, 16, 0, 0);
}
__device__ __forceinline__ bf16x8 pack8(const float4* br, int c) {
  union { bf16x8 v; unsigned u[4]; } p;
  p.u[0] = cvtpk((&br[0].x)[c], (&br[1].x)[c]);
  p.u[1] = cvtpk((&br[2].x)[c], (&br[3].x)[c]);
  p.u[2] = cvtpk((&br[4].x)[c], (&br[5].x)[c]);
  p.u[3] = cvtpk((&br[6].x)[c], (&br[7].x)[c]);
  return p.v;
}

// ---------------- router ----------------
__global__ void router_kernel(const float* __restrict__ x, const float* __restrict__ Wr,
                              int* __restrict__ cnt, int* __restrict__ tok,
                              float* __restrict__ prb) {
  int t = (blockIdx.x * blockDim.x + threadIdx.x) >> 6;
  int lane = threadIdx.x & 63;
  if (t >= T_TOK) return;
  const float* xr = x + (size_t)t * DDIM;
  float acc[NEXP];
#pragma unroll
  for (int e = 0; e < NEXP; ++e) acc[e] = 0.f;
#pragma unroll
  for (int i = 0; i < 4; ++i) {
    int d0 = lane * 16 + i * 4;
    float4 xv = *reinterpret_cast<const float4*>(xr + d0);
#pragma unroll
    for (int j = 0; j < 4; ++j) {
      float xd = (&xv.x)[j];
      float4 w0 = *reinterpret_cast<const float4*>(Wr + (size_t)(d0 + j) * NEXP);
      float4 w1 = *reinterpret_cast<const float4*>(Wr + (size_t)(d0 + j) * NEXP + 4);
      acc[0] += xd * w0.x; acc[1] += xd * w0.y; acc[2] += xd * w0.z; acc[3] += xd * w0.w;
      acc[4] += xd * w1.x; acc[5] += xd * w1.y; acc[6] += xd * w1.z; acc[7] += xd * w1.w;
    }
  }
#pragma unroll
  for (int off = 32; off >= 1; off >>= 1)
#pragma unroll
    for (int e = 0; e < NEXP; ++e) acc[e] += __shfl_down(acc[e], off);
  if (lane == 0) {
    float v0 = -1e30f, v1 = -1e30f; int i0 = 0, i1 = 0;
#pragma unroll
    for (int e = 0; e < NEXP; ++e) {
      float v = acc[e];
      if (v > v0)      { v1 = v0; i1 = i0; v0 = v; i0 = e; }
      else if (v > v1) { v1 = v; i1 = e; }
    }
    float e1 = __expf(v1 - v0);
    float p0 = 1.f / (1.f + e1);
    float p1 = e1 * p0;
    int s0 = atomicAdd(&cnt[i0], 1);
    tok[i0 * T_TOK + s0] = t; prb[i0 * T_TOK + s0] = p0;
    int s1 = atomicAdd(&cnt[i1], 1);
    tok[i1 * T_TOK + s1] = t; prb[i1 * T_TOK + s1] = p1;
  }
}

// ---------------- x fp32 -> bf16 ----------------
__global__ void cvt_x_kernel(const float* __restrict__ in, unsigned short* __restrict__ o) {
  size_t i = ((size_t)blockIdx.x * 256 + threadIdx.x) * 8;
  float4 a = *reinterpret_cast<const float4*>(in + i);
  float4 b = *reinterpret_cast<const float4*>(in + i + 4);
  bf16x8 p;
  p[0] = (short)f2b(a.x); p[1] = (short)f2b(a.y); p[2] = (short)f2b(a.z); p[3] = (short)f2b(a.w);
  p[4] = (short)f2b(b.x); p[5] = (short)f2b(b.y); p[6] = (short)f2b(b.z); p[7] = (short)f2b(b.w);
  *reinterpret_cast<bf16x8*>(o + i) = p;
}

// =====================================================================
// ffn1s: W1/W3 panel (32 n-cols x full K=1024) resident in LDS; tokens
// stream through with NO barriers, NO LDS A-traffic. 8 waves m-stacked,
// wave tile 64m x 32n(h) + 32n(g), acc 4m x (2+2)n.
// =====================================================================
__global__ __launch_bounds__(512, 1)
void ffn1s_kernel(const unsigned short* __restrict__ xb,
                  const float* __restrict__ W1, const float* __restrict__ W3,
                  const int* __restrict__ cnt, const int* __restrict__ tok,
                  unsigned short* __restrict__ act) {
  const int e = blockIdx.z;
  const int p = blockIdx.x;          // n-panel [0, 128)
  const int cn = cnt[e];
  if (cn <= 0) return;
  int off = 0;
#pragma unroll
  for (int i = 0; i < NEXP; ++i) off += (i < e) ? cnt[i] : 0;

  // [W1|W3][n:32][k:1024] bf16, b128 slots XOR-swizzled by (n&7). 128 KB.
  __shared__ __align__(16) unsigned short sW[2][32 * 1024];

  const int tid = threadIdx.x;       // 0..511
  const int lane = tid & 63;
  const int w = tid >> 6;            // 0..7

  // ---------- init: load + cvt + transpose-pack the W panel ----------
  {
    const int m01 = tid >> 8;          // 0 -> W1, 1 -> W3
    const int t = tid & 255;
    const int np = (t & 15) * 2;       // n pair base 0..30
    const int kg = (t >> 4) * 8;       // 0..120
    const float* src = (m01 ? W3 : W1) + (size_t)e * DDIM * FDIM + p * 32 + np;
    unsigned short* dst = &sW[m01][0];
#pragma unroll
    for (int it = 0; it < 8; ++it) {
      int kb = it * 128 + kg;
      float2 br2[8];
#pragma unroll
      for (int r = 0; r < 8; ++r)
        br2[r] = *reinterpret_cast<const float2*>(src + (size_t)(kb + r) * FDIM);
      int s = kb >> 3;                 // slot 0..127
#pragma unroll
      for (int c = 0; c < 2; ++c) {
        int n = np + c;
        union { bf16x8 v; unsigned u[4]; } pk;
        pk.u[0] = cvtpk((&br2[0].x)[c], (&br2[1].x)[c]);
        pk.u[1] = cvtpk((&br2[2].x)[c], (&br2[3].x)[c]);
        pk.u[2] = cvtpk((&br2[4].x)[c], (&br2[5].x)[c]);
        pk.u[3] = cvtpk((&br2[6].x)[c], (&br2[7].x)[c]);
        *reinterpret_cast<bf16x8*>(&dst[n * 1024 + ((s ^ (n & 7)) << 3)]) = pk.v;
      }
    }
  }
  __syncthreads();   // publish sW; read-only afterwards -> no further barriers

  const int lq = lane >> 4;          // k-octet 0..3
  const int ln = lane & 15;

  const int nch = (cn + 511) >> 9;
  for (int ch = 0; ch < nch; ++ch) {
    // per-lane token-row bases for the 4 m-frags
    const unsigned short* ab[4];
#pragma unroll
    for (int m = 0; m < 4; ++m) {
      int row = ch * 512 + w * 64 + m * 16 + ln;
      int slot = row < cn ? row : cn - 1;
      int tk = tok[e * T_TOK + slot];
      ab[m] = xb + (size_t)tk * DDIM + lq * 8;
    }

    f32x4 ah[4][2], ag[4][2];
#pragma unroll
    for (int m = 0; m < 4; ++m)
#pragma unroll
      for (int n = 0; n < 2; ++n) { ah[m][n] = (f32x4){0,0,0,0}; ag[m][n] = (f32x4){0,0,0,0}; }

#pragma unroll 8
    for (int kk = 0; kk < 32; ++kk) {
      bf16x8 a[4], b1[2], b3[2];
#pragma unroll
      for (int m = 0; m < 4; ++m)
        a[m] = *reinterpret_cast<const bf16x8*>(ab[m] + kk * 32);
#pragma unroll
      for (int n = 0; n < 2; ++n) {
        int row = n * 16 + ln;
        int sl = (((kk * 4 + lq) ^ (row & 7)) << 3);
        b1[n] = *reinterpret_cast<const bf16x8*>(&sW[0][row * 1024 + sl]);
        b3[n] = *reinterpret_cast<const bf16x8*>(&sW[1][row * 1024 + sl]);
      }
#pragma unroll
      for (int m = 0; m < 4; ++m)
#pragma unroll
        for (int n = 0; n < 2; ++n) {
          ah[m][n] = __builtin_amdgcn_mfma_f32_16x16x32_bf16(a[m], b1[n], ah[m][n], 0, 0, 0);
          ag[m][n] = __builtin_amdgcn_mfma_f32_16x16x32_bf16(a[m], b3[n], ag[m][n], 0, 0, 0);
        }
    }

    // epilogue: act = silu(h) * g
#pragma unroll
    for (int m = 0; m < 4; ++m)
#pragma unroll
      for (int j = 0; j < 4; ++j) {
        int s = ch * 512 + w * 64 + m * 16 + lq * 4 + j;
        if (s < cn) {
          unsigned short* orow = act + (size_t)(off + s) * FDIM + p * 32 + ln;
#pragma unroll
          for (int n = 0; n < 2; ++n) {
            float hv = ah[m][n][j];
            float gv = ag[m][n][j];
            float sg = hv / (1.f + __expf(-hv));
            orow[n * 16] = f2b(sg * gv);
          }
        }
      }
  }
}

// ======== GEMM2: out += p * act @ W2 (direct fp32 W2, split-K=4, atomics) ====
// R11-verbatim. Tile 128m x 128n, 4 waves, 3 blocks/CU.
__global__ __launch_bounds__(256, 3)
void gemm2d_kernel(const unsigned short* __restrict__ act, const float* __restrict__ W2,
                   const int* __restrict__ cnt, const int* __restrict__ tok,
                   const float* __restrict__ prb, float* __restrict__ out) {
  const int e = blockIdx.z >> 2;
  const int sp = blockIdx.z & 3;
  const int cn = cnt[e];
  const int r0 = blockIdx.y * 128;
  if (r0 >= cn) return;
  const int n0 = blockIdx.x * 128;
  const int kbase = sp * (FDIM / 4);
  int off = 0;
#pragma unroll
  for (int i = 0; i < NEXP; ++i) off += (i < e) ? cnt[i] : 0;

  __shared__ __align__(16) unsigned short sA[128 * 64];      // 16 KB
  __shared__ __align__(16) unsigned short sB[128 * 64];      // 16 KB

  const int tid = threadIdx.x;
  const int lane = tid & 63;
  const int wid = tid >> 6;
  const int wm = wid >> 1, wn = wid & 1;

  const unsigned short* asrc[4];
#pragma unroll
  for (int i = 0; i < 4; ++i) {
    int row = (4 * wid + i) * 8 + (lane >> 3);
    int sl = (lane & 7) ^ (row & 7);
    asrc[i] = act + (size_t)(off + r0 + row) * FDIM + kbase + sl * 8;
  }

  const int ko = tid >> 5;          // 0..7
  const int nc = (tid & 31) * 4;    // 0..124
  const float* bp = W2 + ((size_t)e * FDIM + kbase + 8 * ko) * DDIM + n0 + nc;
  int woff[4];
#pragma unroll
  for (int c = 0; c < 4; ++c) woff[c] = (nc + c) * 64 + ((ko ^ SBW(nc + c)) * 8);

  float4 br[8];
#define LOADB2(K0)                                                              \
  _Pragma("unroll") for (int r = 0; r < 8; ++r)                                 \
      br[r] = *reinterpret_cast<const float4*>(bp + (size_t)((K0) + r) * DDIM);
#define WRITEB2()                                                               \
  _Pragma("unroll") for (int c = 0; c < 4; ++c)                                 \
      *reinterpret_cast<bf16x8*>(&sB[woff[c]]) = pack8(br, c);
#define STAGEA2(K0)                                                             \
  _Pragma("unroll") for (int i = 0; i < 4; ++i)                                 \
      gl16(asrc[i] + (K0), &sA[(4 * wid + i) * 512]);

  f32x4 acc[4][4];
#pragma unroll
  for (int m = 0; m < 4; ++m)
#pragma unroll
    for (int n = 0; n < 4; ++n) acc[m][n] = (f32x4){0,0,0,0};

  LOADB2(0);

  for (int k0 = 0; k0 < FDIM / 4; k0 += 64) {
    WRITEB2();
    STAGEA2(k0);
    __syncthreads();
    if (k0 + 64 < FDIM / 4) LOADB2(k0 + 64);
#pragma unroll
    for (int kk = 0; kk < 2; ++kk) {
      int kc8 = kk * 4 + (lane >> 4);
      bf16x8 a[4], b[4];
#pragma unroll
      for (int m = 0; m < 4; ++m) {
        int row = wm * 64 + m * 16 + (lane & 15);
        a[m] = *reinterpret_cast<const bf16x8*>(&sA[row * 64 + ((kc8 ^ (row & 7)) * 8)]);
      }
#pragma unroll
      for (int n = 0; n < 4; ++n) {
        int col = wn * 64 + n * 16 + (lane & 15);
        b[n] = *reinterpret_cast<const bf16x8*>(&sB[col * 64 + ((kc8 ^ SBW(col)) * 8)]);
      }
#pragma unroll
      for (int m = 0; m < 4; ++m)
#pragma unroll
        for (int n = 0; n < 4; ++n)
          acc[m][n] = __builtin_amdgcn_mfma_f32_16x16x32_bf16(a[m], b[n], acc[m][n], 0, 0, 0);
    }
    __syncthreads();
  }
#pragma unroll
  for (int m = 0; m < 4; ++m)
#pragma unroll
    for (int j = 0; j < 4; ++j) {
      int rloc = wm * 64 + m * 16 + (lane >> 4) * 4 + j;
      int s = r0 + rloc;
      if (s < cn) {
        int tkn = tok[e * T_TOK + s];
        float p = prb[e * T_TOK + s];
        float* orow = out + (size_t)tkn * DDIM + n0 + wn * 64 + (lane & 15);
#pragma unroll
        for (int n = 0; n < 4; ++n) atomicAdd(&orow[n * 16], p * acc[m][n][j]);
      }
    }
}

// ============================================================================
extern "C" void kernel_launch(void* const* d_in, const int* in_sizes, int n_in,
                              void* d_out, int out_size, void* d_ws, size_t ws_size,
                              hipStream_t stream) {
  const float* x  = (const float*)d_in[0];
  const float* Wr = (const float*)d_in[1];
  const float* W1 = (const float*)d_in[2];
  const float* W2 = (const float*)d_in[3];
  const float* W3 = (const float*)d_in[4];
  float* out = (float*)d_out;

  char* ws = (char*)d_ws;
  int*   cnt = (int*)ws;                      // 32 B
  int*   tok = (int*)(ws + 1024);             // 64 KB
  float* prb = (float*)(ws + 1024 + 65536);   // 64 KB
  unsigned short* xb  = (unsigned short*)(ws + 256 * 1024);   // 4 MB
  unsigned short* act = xb + (size_t)T_TOK * DDIM;            // ROWS x FDIM bf16

  hipMemsetAsync(cnt, 0, NEXP * sizeof(int), stream);
  hipMemsetAsync(d_out, 0, (size_t)out_size * sizeof(float), stream);

  router_kernel<<<T_TOK / 4, 256, 0, stream>>>(x, Wr, cnt, tok, prb);
  cvt_x_kernel<<<(T_TOK * DDIM) / (256 * 8), 256, 0, stream>>>(x, xb);
  ffn1s_kernel<<<dim3(FDIM / 32, 1, NEXP), 512, 0, stream>>>(xb, W1, W3, cnt, tok, act);
  gemm2d_kernel<<<dim3(DDIM / 128, 16, NEXP * 4), 256, 0, stream>>>(act, W2, cnt, tok, prb, out);
}

// Round 14
// 294.716 us; speedup vs baseline: 1.2918x; 1.2918x over previous
//
#include <hip/hip_runtime.h>
#include <hip/hip_bf16.h>

#define T_TOK 2048
#define DDIM  1024
#define NEXP  8
#define FDIM  4096
#define ROWS  (4096 + 256)

typedef __attribute__((ext_vector_type(8))) short bf16x8;
typedef __attribute__((ext_vector_type(4))) float f32x4;

#define SBW(n) ((((n) >> 3) ^ (n)) & 7)

__device__ __forceinline__ unsigned short f2b(float f) {
  union { float f; unsigned u; } v; v.f = f;
  unsigned r = v.u + 0x7FFF + ((v.u >> 16) & 1);  // RNE
  return (unsigned short)(r >> 16);
}
__device__ __forceinline__ float b2f(unsigned short s) {
  union { unsigned u; float f; } v; v.u = ((unsigned)s) << 16;
  return v.f;
}
__device__ __forceinline__ unsigned cvtpk(float lo, float hi) {
  unsigned r;
  asm("v_cvt_pk_bf16_f32 %0, %1, %2" : "=v"(r) : "v"(lo), "v"(hi));
  return r;
}
__device__ __forceinline__ void gl16(const unsigned short* g, unsigned short* l) {
  __builtin_amdgcn_global_load_lds(
      (const __attribute__((address_space(1))) unsigned int*)(const void*)g,
      (__attribute__((address_space(3))) unsigned int*)(void*)l, 16, 0, 0);
}
// pack 8 k-consecutive bf16 (column c of 8 float4 rows)
__device__ __forceinline__ bf16x8 pack8(const float4* br, int c) {
  union { bf16x8 v; unsigned u[4]; } p;
  p.u[0] = cvtpk((&br[0].x)[c], (&br[1].x)[c]);
  p.u[1] = cvtpk((&br[2].x)[c], (&br[3].x)[c]);
  p.u[2] = cvtpk((&br[4].x)[c], (&br[5].x)[c]);
  p.u[3] = cvtpk((&br[6].x)[c], (&br[7].x)[c]);
  return p.v;
}

// ---------------- router ----------------
__global__ void router_kernel(const float* __restrict__ x, const float* __restrict__ Wr,
                              int* __restrict__ cnt, int* __restrict__ tok,
                              float* __restrict__ prb) {
  int t = (blockIdx.x * blockDim.x + threadIdx.x) >> 6;
  int lane = threadIdx.x & 63;
  if (t >= T_TOK) return;
  const float* xr = x + (size_t)t * DDIM;
  float acc[NEXP];
#pragma unroll
  for (int e = 0; e < NEXP; ++e) acc[e] = 0.f;
#pragma unroll
  for (int i = 0; i < 4; ++i) {
    int d0 = lane * 16 + i * 4;
    float4 xv = *reinterpret_cast<const float4*>(xr + d0);
#pragma unroll
    for (int j = 0; j < 4; ++j) {
      float xd = (&xv.x)[j];
      float4 w0 = *reinterpret_cast<const float4*>(Wr + (size_t)(d0 + j) * NEXP);
      float4 w1 = *reinterpret_cast<const float4*>(Wr + (size_t)(d0 + j) * NEXP + 4);
      acc[0] += xd * w0.x; acc[1] += xd * w0.y; acc[2] += xd * w0.z; acc[3] += xd * w0.w;
      acc[4] += xd * w1.x; acc[5] += xd * w1.y; acc[6] += xd * w1.z; acc[7] += xd * w1.w;
    }
  }
#pragma unroll
  for (int off = 32; off >= 1; off >>= 1)
#pragma unroll
    for (int e = 0; e < NEXP; ++e) acc[e] += __shfl_down(acc[e], off);
  if (lane == 0) {
    float v0 = -1e30f, v1 = -1e30f; int i0 = 0, i1 = 0;
#pragma unroll
    for (int e = 0; e < NEXP; ++e) {
      float v = acc[e];
      if (v > v0)      { v1 = v0; i1 = i0; v0 = v; i0 = e; }
      else if (v > v1) { v1 = v; i1 = e; }
    }
    float e1 = __expf(v1 - v0);
    float p0 = 1.f / (1.f + e1);
    float p1 = e1 * p0;
    int s0 = atomicAdd(&cnt[i0], 1);
    tok[i0 * T_TOK + s0] = t; prb[i0 * T_TOK + s0] = p0;
    int s1 = atomicAdd(&cnt[i1], 1);
    tok[i1 * T_TOK + s1] = t; prb[i1 * T_TOK + s1] = p1;
  }
}

// ---------------- gather+cvt: xg[off_e + s] = bf16(x[tok[e][s]]) ----------------
// Sum_e cnt[e] == 2*T_TOK == 4096 always (top-2 of distinct experts).
__global__ void gather_x_kernel(const float* __restrict__ x, const int* __restrict__ cnt,
                                const int* __restrict__ tok, unsigned short* __restrict__ xg) {
  int gs = blockIdx.x * 4 + (threadIdx.x >> 6);   // global slot [0, 4096)
  int lane = threadIdx.x & 63;
  int s = gs, e = 0;
#pragma unroll
  for (int i = 0; i < NEXP - 1; ++i) {
    int c = cnt[i];
    bool go = (e == i) && (s >= c);
    if (go) { s -= c; e = i + 1; }
  }
  int tk = tok[e * T_TOK + s];
  const float* src = x + (size_t)tk * DDIM;
  unsigned short* dst = xg + (size_t)gs * DDIM;
#pragma unroll
  for (int it = 0; it < 4; ++it) {
    float4 v = *reinterpret_cast<const float4*>(src + it * 256 + lane * 4);
    uint2 p;
    p.x = cvtpk(v.x, v.y);
    p.y = cvtpk(v.z, v.w);
    *reinterpret_cast<uint2*>(dst + it * 256 + lane * 4) = p;
  }
}

// ======== fused GEMM1: act = silu(xg@W1) * (xg@W3), direct fp32 weights ======
// R11 body with DENSE A (compacted xg) -- no per-lane token gather in loop.
__global__ __launch_bounds__(256, 3)
void gemm1ab_kernel(const unsigned short* __restrict__ xg,
                    const float* __restrict__ W1, const float* __restrict__ W3,
                    const int* __restrict__ cnt,
                    unsigned short* __restrict__ act) {
  const int e = blockIdx.z;
  const int cn = cnt[e];
  const int r0 = blockIdx.y * 128;
  if (r0 >= cn) return;
  const int n0 = blockIdx.x * 64;
  int off = 0;
#pragma unroll
  for (int i = 0; i < NEXP; ++i) off += (i < e) ? cnt[i] : 0;

  __shared__ __align__(16) unsigned short sA[128 * 64];      // 16 KB
  __shared__ __align__(16) unsigned short sB1[64 * 64];      // 8 KB
  __shared__ __align__(16) unsigned short sB3[64 * 64];      // 8 KB

  const int tid = threadIdx.x;
  const int lane = tid & 63;
  const int wid = tid >> 6;
  const int wm = wid >> 1, wn = wid & 1;

  // A staging: DENSE rows off+r0+row (over-reads masked at epilogue)
  const unsigned short* asrc[4];
#pragma unroll
  for (int i = 0; i < 4; ++i) {
    int row = (4 * wid + i) * 8 + (lane >> 3);
    int sl = (lane & 7) ^ (row & 7);
    asrc[i] = xg + (size_t)(off + r0 + row) * DDIM + sl * 8;
  }

  // B staging: tid<128 stages W1, tid>=128 stages W3; thread owns 8k x 4n.
  const int lt = tid & 127;
  const int ko = lt >> 4;           // 0..7
  const int nc = (lt & 15) * 4;     // 0..60
  const float* bp = ((tid < 128) ? W1 : W3) + ((size_t)e * DDIM + 8 * ko) * FDIM + n0 + nc;
  unsigned short* wb = (tid < 128) ? sB1 : sB3;
  int woff[4];
#pragma unroll
  for (int c = 0; c < 4; ++c) woff[c] = (nc + c) * 64 + ((ko ^ SBW(nc + c)) * 8);

  float4 br[8];
#define LOADB1(K0)                                                              \
  _Pragma("unroll") for (int r = 0; r < 8; ++r)                                 \
      br[r] = *reinterpret_cast<const float4*>(bp + (size_t)((K0) + r) * FDIM);
#define WRITEB1()                                                               \
  _Pragma("unroll") for (int c = 0; c < 4; ++c)                                 \
      *reinterpret_cast<bf16x8*>(wb + woff[c]) = pack8(br, c);
#define STAGEA1(K0)                                                             \
  _Pragma("unroll") for (int i = 0; i < 4; ++i)                                 \
      gl16(asrc[i] + (K0), &sA[(4 * wid + i) * 512]);

  f32x4 ah[4][2], ag[4][2];
#pragma unroll
  for (int m = 0; m < 4; ++m)
#pragma unroll
    for (int n = 0; n < 2; ++n) { ah[m][n] = (f32x4){0,0,0,0}; ag[m][n] = (f32x4){0,0,0,0}; }

  LOADB1(0);

  for (int k0 = 0; k0 < DDIM; k0 += 64) {
    WRITEB1();
    STAGEA1(k0);
    __syncthreads();
    if (k0 + 64 < DDIM) LOADB1(k0 + 64);
#pragma unroll
    for (int kk = 0; kk < 2; ++kk) {
      int kc8 = kk * 4 + (lane >> 4);
      bf16x8 a[4], b1[2], b3[2];
#pragma unroll
      for (int m = 0; m < 4; ++m) {
        int row = wm * 64 + m * 16 + (lane & 15);
        a[m] = *reinterpret_cast<const bf16x8*>(&sA[row * 64 + ((kc8 ^ (row & 7)) * 8)]);
      }
#pragma unroll
      for (int n = 0; n < 2; ++n) {
        int rowb = wn * 32 + n * 16 + (lane & 15);
        int offb = rowb * 64 + ((kc8 ^ SBW(rowb)) * 8);
        b1[n] = *reinterpret_cast<const bf16x8*>(&sB1[offb]);
        b3[n] = *reinterpret_cast<const bf16x8*>(&sB3[offb]);
      }
#pragma unroll
      for (int m = 0; m < 4; ++m)
#pragma unroll
        for (int n = 0; n < 2; ++n) {
          ah[m][n] = __builtin_amdgcn_mfma_f32_16x16x32_bf16(a[m], b1[n], ah[m][n], 0, 0, 0);
          ag[m][n] = __builtin_amdgcn_mfma_f32_16x16x32_bf16(a[m], b3[n], ag[m][n], 0, 0, 0);
        }
    }
    __syncthreads();
  }
  // epilogue: act = silu(h) * g
#pragma unroll
  for (int m = 0; m < 4; ++m)
#pragma unroll
    for (int j = 0; j < 4; ++j) {
      int rloc = wm * 64 + m * 16 + (lane >> 4) * 4 + j;
      int s = r0 + rloc;
      if (s < cn) {
        unsigned short* orow = act + (size_t)(off + s) * FDIM + n0 + wn * 32 + (lane & 15);
#pragma unroll
        for (int n = 0; n < 2; ++n) {
          float hv = ah[m][n][j];
          float gv = ag[m][n][j];
          float sg = hv / (1.f + __expf(-hv));
          orow[n * 16] = f2b(sg * gv);
        }
      }
    }
}

// ======== GEMM2: out += p * act @ W2 (direct fp32 W2, split-K=2, atomics) ====
// R11 body, split-K 4->2 (halved atomic partial-sum traffic).
__global__ __launch_bounds__(256, 3)
void gemm2d_kernel(const unsigned short* __restrict__ act, const float* __restrict__ W2,
                   const int* __restrict__ cnt, const int* __restrict__ tok,
                   const float* __restrict__ prb, float* __restrict__ out) {
  const int e = blockIdx.z >> 1;
  const int sp = blockIdx.z & 1;
  const int cn = cnt[e];
  const int r0 = blockIdx.y * 128;
  if (r0 >= cn) return;
  const int n0 = blockIdx.x * 128;
  const int kbase = sp * (FDIM / 2);
  int off = 0;
#pragma unroll
  for (int i = 0; i < NEXP; ++i) off += (i < e) ? cnt[i] : 0;

  __shared__ __align__(16) unsigned short sA[128 * 64];      // 16 KB
  __shared__ __align__(16) unsigned short sB[128 * 64];      // 16 KB

  const int tid = threadIdx.x;
  const int lane = tid & 63;
  const int wid = tid >> 6;
  const int wm = wid >> 1, wn = wid & 1;

  const unsigned short* asrc[4];
#pragma unroll
  for (int i = 0; i < 4; ++i) {
    int row = (4 * wid + i) * 8 + (lane >> 3);
    int sl = (lane & 7) ^ (row & 7);
    asrc[i] = act + (size_t)(off + r0 + row) * FDIM + kbase + sl * 8;
  }

  const int ko = tid >> 5;          // 0..7
  const int nc = (tid & 31) * 4;    // 0..124
  const float* bp = W2 + ((size_t)e * FDIM + kbase + 8 * ko) * DDIM + n0 + nc;
  int woff[4];
#pragma unroll
  for (int c = 0; c < 4; ++c) woff[c] = (nc + c) * 64 + ((ko ^ SBW(nc + c)) * 8);

  float4 br[8];
#define LOADB2(K0)                                                              \
  _Pragma("unroll") for (int r = 0; r < 8; ++r)                                 \
      br[r] = *reinterpret_cast<const float4*>(bp + (size_t)((K0) + r) * DDIM);
#define WRITEB2()                                                               \
  _Pragma("unroll") for (int c = 0; c < 4; ++c)                                 \
      *reinterpret_cast<bf16x8*>(&sB[woff[c]]) = pack8(br, c);
#define STAGEA2(K0)                                                             \
  _Pragma("unroll") for (int i = 0; i < 4; ++i)                                 \
      gl16(asrc[i] + (K0), &sA[(4 * wid + i) * 512]);

  f32x4 acc[4][4];
#pragma unroll
  for (int m = 0; m < 4; ++m)
#pragma unroll
    for (int n = 0; n < 4; ++n) acc[m][n] = (f32x4){0,0,0,0};

  LOADB2(0);

  for (int k0 = 0; k0 < FDIM / 2; k0 += 64) {
    WRITEB2();
    STAGEA2(k0);
    __syncthreads();
    if (k0 + 64 < FDIM / 2) LOADB2(k0 + 64);
#pragma unroll
    for (int kk = 0; kk < 2; ++kk) {
      int kc8 = kk * 4 + (lane >> 4);
      bf16x8 a[4], b[4];
#pragma unroll
      for (int m = 0; m < 4; ++m) {
        int row = wm * 64 + m * 16 + (lane & 15);
        a[m] = *reinterpret_cast<const bf16x8*>(&sA[row * 64 + ((kc8 ^ (row & 7)) * 8)]);
      }
#pragma unroll
      for (int n = 0; n < 4; ++n) {
        int col = wn * 64 + n * 16 + (lane & 15);
        b[n] = *reinterpret_cast<const bf16x8*>(&sB[col * 64 + ((kc8 ^ SBW(col)) * 8)]);
      }
#pragma unroll
      for (int m = 0; m < 4; ++m)
#pragma unroll
        for (int n = 0; n < 4; ++n)
          acc[m][n] = __builtin_amdgcn_mfma_f32_16x16x32_bf16(a[m], b[n], acc[m][n], 0, 0, 0);
    }
    __syncthreads();
  }
#pragma unroll
  for (int m = 0; m < 4; ++m)
#pragma unroll
    for (int j = 0; j < 4; ++j) {
      int rloc = wm * 64 + m * 16 + (lane >> 4) * 4 + j;
      int s = r0 + rloc;
      if (s < cn) {
        int tkn = tok[e * T_TOK + s];
        float p = prb[e * T_TOK + s];
        float* orow = out + (size_t)tkn * DDIM + n0 + wn * 64 + (lane & 15);
#pragma unroll
        for (int n = 0; n < 4; ++n) atomicAdd(&orow[n * 16], p * acc[m][n][j]);
      }
    }
}

// ============================================================================
extern "C" void kernel_launch(void* const* d_in, const int* in_sizes, int n_in,
                              void* d_out, int out_size, void* d_ws, size_t ws_size,
                              hipStream_t stream) {
  const float* x  = (const float*)d_in[0];
  const float* Wr = (const float*)d_in[1];
  const float* W1 = (const float*)d_in[2];
  const float* W2 = (const float*)d_in[3];
  const float* W3 = (const float*)d_in[4];
  float* out = (float*)d_out;

  char* ws = (char*)d_ws;
  int*   cnt = (int*)ws;                      // 32 B
  int*   tok = (int*)(ws + 1024);             // 64 KB
  float* prb = (float*)(ws + 1024 + 65536);   // 64 KB
  unsigned short* xg  = (unsigned short*)(ws + 256 * 1024);   // ROWS x DDIM bf16 (~8.9 MB)
  unsigned short* act = xg + (size_t)ROWS * DDIM;             // ROWS x FDIM bf16

  hipMemsetAsync(cnt, 0, NEXP * sizeof(int), stream);
  hipMemsetAsync(d_out, 0, (size_t)out_size * sizeof(float), stream);

  router_kernel<<<T_TOK / 4, 256, 0, stream>>>(x, Wr, cnt, tok, prb);
  gather_x_kernel<<<(2 * T_TOK) / 4, 256, 0, stream>>>(x, cnt, tok, xg);
  gemm1ab_kernel<<<dim3(FDIM / 64, 16, NEXP), 256, 0, stream>>>(xg, W1, W3, cnt, act);
  gemm2d_kernel<<<dim3(DDIM / 128, 16, NEXP * 2), 256, 0, stream>>>(act, W2, cnt, tok, prb, out);
}